// Round 3
// baseline (233.830 us; speedup 1.0000x reference)
//
#include <hip/hip_runtime.h>

typedef __fp16 fp16x2 __attribute__((ext_vector_type(2)));   // cvt_pkrtz result type
typedef _Float16 half8 __attribute__((ext_vector_type(8)));
typedef float floatx4 __attribute__((ext_vector_type(4)));

namespace {

constexpr int NODES = 512;   // nodes per graph
constexpr int DIM   = 256;   // latent dim
constexpr int BM    = 128;   // block tile (rows and cols)
constexpr int BK    = 64;    // K-step per LDS stage
constexpr int LSTR  = 72;    // padded LDS row stride in halfs (144 B: 16B-aligned,
                             // bank stride 36%32=4 -> 2-way on frag reads = free)

union Cvt8 { fp16x2 h2[4]; half8 h8; };

__device__ inline half8 pack8(const float4 f0, const float4 f1) {
  Cvt8 c;
  c.h2[0] = __builtin_amdgcn_cvt_pkrtz(f0.x, f0.y);
  c.h2[1] = __builtin_amdgcn_cvt_pkrtz(f0.z, f0.w);
  c.h2[2] = __builtin_amdgcn_cvt_pkrtz(f1.x, f1.y);
  c.h2[3] = __builtin_amdgcn_cvt_pkrtz(f1.z, f1.w);
  return c.h8;
}

// 2048 blocks = 128 graphs x 16 tiles; 256 threads = 4 waves; each wave a
// 64x64 sub-tile via 4x4 mfma_f32_16x16x32_f16 accumulators.
__global__ __launch_bounds__(256, 4)
void decoder_kernel(const float* __restrict__ z, float* __restrict__ out) {
  __shared__ _Float16 As[BM * LSTR];
  __shared__ _Float16 Bs[BM * LSTR];

  const int bid = blockIdx.x;
  // XCD-aware swizzle: all 16 tiles of a graph share bid%8 (-> same XCD),
  // so each XCD's L2 streams only 16 graphs' z (8 MB) instead of all 128.
  const int g    = (bid & 7) + 8 * (bid >> 7);
  const int tile = (bid >> 3) & 15;
  const int tn   = tile >> 2;      // row-tile (n)
  const int tm   = tile & 3;       // col-tile (m)

  const int tid  = threadIdx.x;
  const int lane = tid & 63;
  const int wave = tid >> 6;
  const int wRow = wave >> 1;      // 0..1
  const int wCol = wave & 1;       // 0..1
  const int lrow = lane & 15;
  const int quad = lane >> 4;      // 0..3

  const float* zA = z + ((size_t)g * NODES + tn * BM) * DIM;
  const float* zB = z + ((size_t)g * NODES + tm * BM) * DIM;

  // staging assignment: thread -> (row, 32-wide k-half)
  const int srow  = tid >> 1;      // 0..127
  const int shalf = tid & 1;       // 0..1

  floatx4 acc[4][4];
#pragma unroll
  for (int i = 0; i < 4; ++i)
#pragma unroll
    for (int j = 0; j < 4; ++j)
      acc[i][j] = (floatx4){0.f, 0.f, 0.f, 0.f};

  for (int kk = 0; kk < DIM; kk += BK) {
    // ---- stage 128x64 fp32 -> fp16 into LDS, both tiles ----
    {
      const float4* pa = reinterpret_cast<const float4*>(zA + srow * DIM + kk + shalf * 32);
      _Float16* da = &As[srow * LSTR + shalf * 32];
      float4 f0 = pa[0], f1 = pa[1], f2 = pa[2], f3 = pa[3];
      *reinterpret_cast<half8*>(da)     = pack8(f0, f1);
      *reinterpret_cast<half8*>(da + 8) = pack8(f2, f3);
      f0 = pa[4]; f1 = pa[5]; f2 = pa[6]; f3 = pa[7];
      *reinterpret_cast<half8*>(da + 16) = pack8(f0, f1);
      *reinterpret_cast<half8*>(da + 24) = pack8(f2, f3);
    }
    {
      const float4* pb = reinterpret_cast<const float4*>(zB + srow * DIM + kk + shalf * 32);
      _Float16* db = &Bs[srow * LSTR + shalf * 32];
      float4 f0 = pb[0], f1 = pb[1], f2 = pb[2], f3 = pb[3];
      *reinterpret_cast<half8*>(db)     = pack8(f0, f1);
      *reinterpret_cast<half8*>(db + 8) = pack8(f2, f3);
      f0 = pb[4]; f1 = pb[5]; f2 = pb[6]; f3 = pb[7];
      *reinterpret_cast<half8*>(db + 16) = pack8(f0, f1);
      *reinterpret_cast<half8*>(db + 24) = pack8(f2, f3);
    }
    __syncthreads();

    // ---- 2 x (8 ds_read_b128 + 16 MFMA) = 32 MFMAs per barrier pair ----
#pragma unroll
    for (int ks = 0; ks < 2; ++ks) {
      half8 af[4], bf[4];
#pragma unroll
      for (int i = 0; i < 4; ++i)
        af[i] = *reinterpret_cast<const half8*>(
            &As[(wRow * 64 + i * 16 + lrow) * LSTR + ks * 32 + quad * 8]);
#pragma unroll
      for (int j = 0; j < 4; ++j)
        bf[j] = *reinterpret_cast<const half8*>(
            &Bs[(wCol * 64 + j * 16 + lrow) * LSTR + ks * 32 + quad * 8]);

#pragma unroll
      for (int i = 0; i < 4; ++i)
#pragma unroll
        for (int j = 0; j < 4; ++j)
          acc[i][j] = __builtin_amdgcn_mfma_f32_16x16x32_f16(af[i], bf[j], acc[i][j], 0, 0, 0);
    }
    __syncthreads();
  }

  // ---- epilogue: sigmoid + fp32 store ----
  float* outg = out + (size_t)g * NODES * NODES;
  const int nBase = tn * BM + wRow * 64;
  const int mBase = tm * BM + wCol * 64;
#pragma unroll
  for (int i = 0; i < 4; ++i) {
#pragma unroll
    for (int j = 0; j < 4; ++j) {
      const int m = mBase + j * 16 + lrow;
#pragma unroll
      for (int r = 0; r < 4; ++r) {
        const int n = nBase + i * 16 + quad * 4 + r;
        const float x = acc[i][j][r];
        outg[(size_t)n * NODES + m] = __builtin_amdgcn_rcpf(1.0f + __expf(-x));
      }
    }
  }
}

} // namespace

extern "C" void kernel_launch(void* const* d_in, const int* in_sizes, int n_in,
                              void* d_out, int out_size, void* d_ws, size_t ws_size,
                              hipStream_t stream) {
  const float* z = (const float*)d_in[0];
  float* out = (float*)d_out;
  dim3 grid(128 * 16);
  dim3 block(256);
  hipLaunchKernelGGL(decoder_kernel, grid, block, 0, stream, z, out);
}

// Round 4
// 217.259 us; speedup vs baseline: 1.0763x; 1.0763x over previous
//
#include <hip/hip_runtime.h>

typedef __fp16 fp16x2 __attribute__((ext_vector_type(2)));   // cvt_pkrtz result type
typedef _Float16 half8 __attribute__((ext_vector_type(8)));
typedef float floatx4 __attribute__((ext_vector_type(4)));

namespace {

constexpr int NODES = 512;   // nodes per graph
constexpr int DIM   = 256;   // latent dim
constexpr int BM    = 128;   // block tile (rows and cols)
constexpr int BK    = 64;    // K-step per LDS stage (fp16): row = 128 B = 8 x 16B chunks

union Cvt8 { fp16x2 h2[4]; half8 h8; };

__device__ inline half8 pack8(const float4 f0, const float4 f1) {
  Cvt8 c;
  c.h2[0] = __builtin_amdgcn_cvt_pkrtz(f0.x, f0.y);
  c.h2[1] = __builtin_amdgcn_cvt_pkrtz(f0.z, f0.w);
  c.h2[2] = __builtin_amdgcn_cvt_pkrtz(f1.x, f1.y);
  c.h2[3] = __builtin_amdgcn_cvt_pkrtz(f1.z, f1.w);
  return c.h8;
}

// async 16-B global -> LDS DMA; LDS dest = wave-uniform base + lane*16
__device__ inline void async_ld16(const void* g, void* lds) {
  __builtin_amdgcn_global_load_lds(
      (const __attribute__((address_space(1))) unsigned int*)g,
      (__attribute__((address_space(3))) unsigned int*)lds,
      16, 0, 0);
}

// ---------- kernel 1: fp32 -> fp16 pre-convert (streaming) ----------
__global__ __launch_bounds__(256)
void cvt_kernel(const float* __restrict__ z, _Float16* __restrict__ z16) {
  const int i = blockIdx.x * 256 + threadIdx.x;   // 8 floats per thread, exact fit
  const float4* p = reinterpret_cast<const float4*>(z) + (size_t)i * 2;
  const float4 f0 = p[0], f1 = p[1];
  reinterpret_cast<half8*>(z16)[i] = pack8(f0, f1);
}

// ---------- kernel 2: batched symmetric GEMM + sigmoid ----------
// 2048 blocks = 128 graphs x 16 tiles; 256 threads = 4 waves; each wave a
// 64x64 sub-tile via 4x4 mfma_f32_16x16x32_f16 accumulators.
// Staging: global_load_lds (16 B), XOR chunk swizzle c' = c ^ (row & 7).
__global__ __launch_bounds__(256, 4)
void gemm_kernel(const _Float16* __restrict__ z16, float* __restrict__ out) {
  __shared__ __align__(16) _Float16 As[BM * BK];   // 16 KB, row = 8 chunks of 16 B
  __shared__ __align__(16) _Float16 Bs[BM * BK];

  const int bid = blockIdx.x;
  // XCD swizzle: all 16 tiles of a graph share bid%8 -> one XCD's L2 holds
  // only 16 graphs' z16 (4.2 MB ~ one L2).
  const int g    = (bid & 7) + 8 * (bid >> 7);
  const int tile = (bid >> 3) & 15;
  const int tn   = tile >> 2;
  const int tm   = tile & 3;

  const int tid  = threadIdx.x;
  const int lane = tid & 63;
  const int wave = tid >> 6;
  const int wRow = wave >> 1;
  const int wCol = wave & 1;
  const int lrow = lane & 15;
  const int quad = lane >> 4;

  const _Float16* zA = z16 + ((size_t)g * NODES + tn * BM) * DIM;
  const _Float16* zB = z16 + ((size_t)g * NODES + tm * BM) * DIM;

  // staging decomposition: 16 instructions/tile, inst q covers rows q*8..q*8+7
  // lane -> (local row = lane>>3, chunk c = lane&7), global chunk = c ^ (row&7)
  const int sRow = lane >> 3;                 // 0..7
  const int sCp  = (lane & 7) ^ sRow;         // swizzled global chunk index
  const size_t sOffH = (size_t)sRow * DIM + sCp * 8;  // halfs, + row-block*8*DIM

  floatx4 acc[4][4];
#pragma unroll
  for (int i = 0; i < 4; ++i)
#pragma unroll
    for (int j = 0; j < 4; ++j)
      acc[i][j] = (floatx4){0.f, 0.f, 0.f, 0.f};

  for (int kk = 0; kk < DIM; kk += BK) {
#pragma unroll
    for (int it = 0; it < 4; ++it) {
      const int q = wave * 4 + it;            // 0..15, rows q*8..q*8+7
      const _Float16* gA = zA + (size_t)q * 8 * DIM + kk + sOffH;
      const _Float16* gB = zB + (size_t)q * 8 * DIM + kk + sOffH;
      async_ld16(gA, &As[q * 512]);           // q*1024 B
      async_ld16(gB, &Bs[q * 512]);
    }
    __syncthreads();                          // drains vmcnt

#pragma unroll
    for (int ks = 0; ks < 2; ++ks) {
      half8 af[4], bf[4];
#pragma unroll
      for (int i = 0; i < 4; ++i) {
        const int row = wRow * 64 + i * 16 + lrow;
        const int cp = (ks * 4 + quad) ^ (lrow & 7);
        af[i] = *reinterpret_cast<const half8*>(&As[row * BK + cp * 8]);
      }
#pragma unroll
      for (int j = 0; j < 4; ++j) {
        const int row = wCol * 64 + j * 16 + lrow;
        const int cp = (ks * 4 + quad) ^ (lrow & 7);
        bf[j] = *reinterpret_cast<const half8*>(&Bs[row * BK + cp * 8]);
      }
#pragma unroll
      for (int i = 0; i < 4; ++i)
#pragma unroll
        for (int j = 0; j < 4; ++j)
          acc[i][j] = __builtin_amdgcn_mfma_f32_16x16x32_f16(af[i], bf[j], acc[i][j], 0, 0, 0);
    }
    __syncthreads();
  }

  // epilogue: sigmoid + fp32 store
  float* outg = out + (size_t)g * NODES * NODES;
  const int nBase = tn * BM + wRow * 64;
  const int mBase = tm * BM + wCol * 64;
#pragma unroll
  for (int i = 0; i < 4; ++i) {
#pragma unroll
    for (int j = 0; j < 4; ++j) {
      const int m = mBase + j * 16 + lrow;
#pragma unroll
      for (int r = 0; r < 4; ++r) {
        const int n = nBase + i * 16 + quad * 4 + r;
        const float x = acc[i][j][r];
        outg[(size_t)n * NODES + m] = __builtin_amdgcn_rcpf(1.0f + __expf(-x));
      }
    }
  }
}

// ---------- fallback (round-3 kernel) if workspace is too small ----------
constexpr int LSTR = 72;
__global__ __launch_bounds__(256, 4)
void fallback_kernel(const float* __restrict__ z, float* __restrict__ out) {
  __shared__ _Float16 As[BM * LSTR];
  __shared__ _Float16 Bs[BM * LSTR];
  const int bid = blockIdx.x;
  const int g    = (bid & 7) + 8 * (bid >> 7);
  const int tile = (bid >> 3) & 15;
  const int tn   = tile >> 2;
  const int tm   = tile & 3;
  const int tid  = threadIdx.x;
  const int lane = tid & 63;
  const int wave = tid >> 6;
  const int wRow = wave >> 1;
  const int wCol = wave & 1;
  const int lrow = lane & 15;
  const int quad = lane >> 4;
  const float* zA = z + ((size_t)g * NODES + tn * BM) * DIM;
  const float* zB = z + ((size_t)g * NODES + tm * BM) * DIM;
  const int srow  = tid >> 1;
  const int shalf = tid & 1;
  floatx4 acc[4][4];
#pragma unroll
  for (int i = 0; i < 4; ++i)
#pragma unroll
    for (int j = 0; j < 4; ++j)
      acc[i][j] = (floatx4){0.f, 0.f, 0.f, 0.f};
  for (int kk = 0; kk < DIM; kk += BK) {
    {
      const float4* pa = reinterpret_cast<const float4*>(zA + srow * DIM + kk + shalf * 32);
      _Float16* da = &As[srow * LSTR + shalf * 32];
      float4 f0 = pa[0], f1 = pa[1], f2 = pa[2], f3 = pa[3];
      *reinterpret_cast<half8*>(da)     = pack8(f0, f1);
      *reinterpret_cast<half8*>(da + 8) = pack8(f2, f3);
      f0 = pa[4]; f1 = pa[5]; f2 = pa[6]; f3 = pa[7];
      *reinterpret_cast<half8*>(da + 16) = pack8(f0, f1);
      *reinterpret_cast<half8*>(da + 24) = pack8(f2, f3);
    }
    {
      const float4* pb = reinterpret_cast<const float4*>(zB + srow * DIM + kk + shalf * 32);
      _Float16* db = &Bs[srow * LSTR + shalf * 32];
      float4 f0 = pb[0], f1 = pb[1], f2 = pb[2], f3 = pb[3];
      *reinterpret_cast<half8*>(db)     = pack8(f0, f1);
      *reinterpret_cast<half8*>(db + 8) = pack8(f2, f3);
      f0 = pb[4]; f1 = pb[5]; f2 = pb[6]; f3 = pb[7];
      *reinterpret_cast<half8*>(db + 16) = pack8(f0, f1);
      *reinterpret_cast<half8*>(db + 24) = pack8(f2, f3);
    }
    __syncthreads();
#pragma unroll
    for (int ks = 0; ks < 2; ++ks) {
      half8 af[4], bf[4];
#pragma unroll
      for (int i = 0; i < 4; ++i)
        af[i] = *reinterpret_cast<const half8*>(
            &As[(wRow * 64 + i * 16 + lrow) * LSTR + ks * 32 + quad * 8]);
#pragma unroll
      for (int j = 0; j < 4; ++j)
        bf[j] = *reinterpret_cast<const half8*>(
            &Bs[(wCol * 64 + j * 16 + lrow) * LSTR + ks * 32 + quad * 8]);
#pragma unroll
      for (int i = 0; i < 4; ++i)
#pragma unroll
        for (int j = 0; j < 4; ++j)
          acc[i][j] = __builtin_amdgcn_mfma_f32_16x16x32_f16(af[i], bf[j], acc[i][j], 0, 0, 0);
    }
    __syncthreads();
  }
  float* outg = out + (size_t)g * NODES * NODES;
  const int nBase = tn * BM + wRow * 64;
  const int mBase = tm * BM + wCol * 64;
#pragma unroll
  for (int i = 0; i < 4; ++i) {
#pragma unroll
    for (int j = 0; j < 4; ++j) {
      const int m = mBase + j * 16 + lrow;
#pragma unroll
      for (int r = 0; r < 4; ++r) {
        const int n = nBase + i * 16 + quad * 4 + r;
        const float x = acc[i][j][r];
        outg[(size_t)n * NODES + m] = __builtin_amdgcn_rcpf(1.0f + __expf(-x));
      }
    }
  }
}

} // namespace

extern "C" void kernel_launch(void* const* d_in, const int* in_sizes, int n_in,
                              void* d_out, int out_size, void* d_ws, size_t ws_size,
                              hipStream_t stream) {
  const float* z = (const float*)d_in[0];
  float* out = (float*)d_out;
  const size_t need = (size_t)128 * 512 * 256 * sizeof(_Float16);  // 33.6 MB
  if (ws_size >= need) {
    _Float16* z16 = (_Float16*)d_ws;
    hipLaunchKernelGGL(cvt_kernel, dim3(8192), dim3(256), 0, stream, z, z16);
    hipLaunchKernelGGL(gemm_kernel, dim3(128 * 16), dim3(256), 0, stream, z16, out);
  } else {
    hipLaunchKernelGGL(fallback_kernel, dim3(128 * 16), dim3(256), 0, stream, z, out);
  }
}